// Round 1
// baseline (294.797 us; speedup 1.0000x reference)
//
#include <hip/hip_runtime.h>
#include <hip/hip_bf16.h>
#include <math.h>

#define HEADS 8
#define D_IN 128
#define D_HEAD 16
#define D_OUT 128  // HEADS * D_HEAD

// ---------------- helpers ----------------
static __device__ inline unsigned short f32_to_bf16(float f) {
    unsigned int u = __float_as_uint(f);
    unsigned int r = (u + 0x7fffu + ((u >> 16) & 1u)) >> 16;  // RTNE
    return (unsigned short)r;
}

// ---------------- kernel 1: feats GEMM + f1/f2 epilogue ----------------
// feats[n][c] = sum_d x[n][d] * W[c>>4][d][c&15]   (stored bf16)
// f1[n][h] = sum_o feats[n][h*16+o]*a1[h][o] + b1[h]; same for f2/a2/b2.
#define BROWS 64
#define KC 32
#define TM 4
#define TN 8

__global__ __launch_bounds__(256) void gemm_feats_kernel(
    const float* __restrict__ x, const float* __restrict__ Wg,
    const float* __restrict__ a1, const float* __restrict__ b1,
    const float* __restrict__ a2, const float* __restrict__ b2,
    unsigned short* __restrict__ feats, float* __restrict__ f1,
    float* __restrict__ f2, int n)
{
    __shared__ float Xs[BROWS][KC + 1];   // 64 x 33 floats (pad breaks bank aliasing)
    __shared__ float Ws[KC][D_OUT];       // 32 x 128 floats

    const int tid = threadIdx.x;
    const int cg  = tid & 15;   // col group: cols cg*8 .. cg*8+7
    const int rg  = tid >> 4;   // row group: rows rg*4 .. rg*4+3
    const int row0 = blockIdx.x * BROWS;

    float acc[TM][TN];
#pragma unroll
    for (int i = 0; i < TM; ++i)
#pragma unroll
        for (int j = 0; j < TN; ++j) acc[i][j] = 0.f;

    for (int kc = 0; kc < D_IN; kc += KC) {
        // stage X tile: 64 rows x 32 k = 512 float4, 2 per thread
#pragma unroll
        for (int q = 0; q < 2; ++q) {
            int idx = q * 256 + tid;        // 0..511
            int r   = idx >> 3;             // 0..63
            int k4  = (idx & 7) * 4;        // 0..28
            int grow = row0 + r;
            float4 v = make_float4(0.f, 0.f, 0.f, 0.f);
            if (grow < n) v = *(const float4*)(x + (size_t)grow * D_IN + kc + k4);
            Xs[r][k4 + 0] = v.x; Xs[r][k4 + 1] = v.y;
            Xs[r][k4 + 2] = v.z; Xs[r][k4 + 3] = v.w;
        }
        // stage W tile: Ws[kk][c] = Wg[(c>>4)*2048 + (kc+kk)*16 + (c&15)]
#pragma unroll
        for (int q = 0; q < 4; ++q) {
            int idx = q * 256 + tid;        // 0..1023
            int kk  = idx >> 5;             // 0..31
            int c4  = (idx & 31) * 4;       // 0..124
            int h   = c4 >> 4;
            int o   = c4 & 15;
            float4 v = *(const float4*)(Wg + (size_t)h * (D_IN * D_HEAD) + (kc + kk) * D_HEAD + o);
            *(float4*)&Ws[kk][c4] = v;
        }
        __syncthreads();

#pragma unroll
        for (int kk = 0; kk < KC; ++kk) {
            float xv[TM];
#pragma unroll
            for (int i = 0; i < TM; ++i) xv[i] = Xs[rg * TM + i][kk];
            float4 w0 = *(float4*)&Ws[kk][cg * 8];
            float4 w1 = *(float4*)&Ws[kk][cg * 8 + 4];
            float wv[TN] = {w0.x, w0.y, w0.z, w0.w, w1.x, w1.y, w1.z, w1.w};
#pragma unroll
            for (int i = 0; i < TM; ++i)
#pragma unroll
                for (int j = 0; j < TN; ++j)
                    acc[i][j] = fmaf(xv[i], wv[j], acc[i][j]);
        }
        __syncthreads();
    }

    // epilogue: this thread's 8 cols live in head h = cg>>1, o offset (cg&1)*8
    const int h  = cg >> 1;
    const int o0 = (cg & 1) * 8;
    float a1v[TN], a2v[TN];
#pragma unroll
    for (int j = 0; j < TN; ++j) {
        a1v[j] = a1[h * D_HEAD + o0 + j];
        a2v[j] = a2[h * D_HEAD + o0 + j];
    }
    const float b1v = b1[h], b2v = b2[h];

#pragma unroll
    for (int i = 0; i < TM; ++i) {
        int grow = row0 + rg * TM + i;
        float s1 = 0.f, s2 = 0.f;
#pragma unroll
        for (int j = 0; j < TN; ++j) {
            s1 = fmaf(acc[i][j], a1v[j], s1);
            s2 = fmaf(acc[i][j], a2v[j], s2);
        }
        // partner thread (tid^1 == lane^1) holds the other half of this head
        s1 += __shfl_xor(s1, 1);
        s2 += __shfl_xor(s2, 1);
        if (grow < n) {
            unsigned int p[4];
#pragma unroll
            for (int j = 0; j < 4; ++j) {
                unsigned int lo = f32_to_bf16(acc[i][2 * j]);
                unsigned int hi = f32_to_bf16(acc[i][2 * j + 1]);
                p[j] = (hi << 16) | lo;
            }
            *(uint4*)(feats + (size_t)grow * D_OUT + cg * 8) =
                make_uint4(p[0], p[1], p[2], p[3]);
            if ((cg & 1) == 0) {
                f1[(size_t)grow * HEADS + h] = s1 + b1v;
                f2[(size_t)grow * HEADS + h] = s2 + b2v;
            }
        }
    }
}

// ---------------- kernel 2: CSR row_ptr from sorted src ----------------
__global__ __launch_bounds__(256) void rowptr_kernel(
    const int* __restrict__ src, int* __restrict__ row_ptr, int n, int e)
{
    int i = blockIdx.x * blockDim.x + threadIdx.x;
    if (i > n) return;
    int lo = 0, hi = e;
    while (lo < hi) {
        int mid = (lo + hi) >> 1;
        if (src[mid] < i) lo = mid + 1; else hi = mid;
    }
    row_ptr[i] = lo;  // lower_bound(src, i)
}

// ---------------- kernel 3: per-node online-softmax aggregation ----------------
// one wave per node; lane owns out channels (2*lane, 2*lane+1); head = lane>>3
__global__ __launch_bounds__(256) void aggregate_kernel(
    const int* __restrict__ row_ptr, const int* __restrict__ dst,
    const unsigned short* __restrict__ feats,
    const float* __restrict__ f1, const float* __restrict__ f2,
    float* __restrict__ out, int n)
{
    int node = blockIdx.x * 4 + (threadIdx.x >> 6);
    if (node >= n) return;
    const int lane = threadIdx.x & 63;
    const int h = lane >> 3;

    const float f1v = f1[(size_t)node * HEADS + h];
    const int start = row_ptr[node];
    const int end   = row_ptr[node + 1];

    float m = -INFINITY, s = 0.f, ax = 0.f, ay = 0.f;

    int d_next = (start < end) ? dst[start] : 0;
    for (int e = start; e < end; ++e) {
        const int d = d_next;
        if (e + 1 < end) d_next = dst[e + 1];   // prefetch next index
        float z = f1v + f2[(size_t)d * HEADS + h];
        z = fmaxf(z, 0.2f * z);                 // leaky_relu(0.2)
        unsigned int p = *(const unsigned int*)(feats + (size_t)d * D_OUT + 2 * lane);
        float fx = __uint_as_float(p << 16);
        float fy = __uint_as_float(p & 0xffff0000u);
        float mn = fmaxf(m, z);
        float alpha = __expf(m - mn);           // first iter: exp(-inf)=0
        float w = __expf(z - mn);
        m = mn;
        s = fmaf(s, alpha, w);
        ax = fmaf(w, fx, ax * alpha);
        ay = fmaf(w, fy, ay * alpha);
    }

    float rx = 0.f, ry = 0.f;
    if (end > start) {
        rx = ax / s;
        ry = ay / s;
        rx = rx > 0.f ? rx : expm1f(rx);        // elu
        ry = ry > 0.f ? ry : expm1f(ry);
    }
    *(float2*)(out + (size_t)node * D_OUT + 2 * lane) = make_float2(rx, ry);
}

// ---------------- launch ----------------
extern "C" void kernel_launch(void* const* d_in, const int* in_sizes, int n_in,
                              void* d_out, int out_size, void* d_ws, size_t ws_size,
                              hipStream_t stream)
{
    const float* x  = (const float*)d_in[0];
    const float* W  = (const float*)d_in[1];
    const float* a1 = (const float*)d_in[2];
    const float* b1 = (const float*)d_in[3];
    const float* a2 = (const float*)d_in[4];
    const float* b2 = (const float*)d_in[5];
    const int* src  = (const int*)d_in[6];
    const int* dst  = (const int*)d_in[7];
    float* out = (float*)d_out;

    const int n = in_sizes[0] / D_IN;   // 100000
    const int e = in_sizes[6];          // 1600000

    // workspace carve-up (~32.4 MB needed)
    char* ws = (char*)d_ws;
    size_t off = 0;
    unsigned short* feats = (unsigned short*)(ws + off);
    off += (size_t)n * D_OUT * sizeof(unsigned short); off = (off + 255) & ~(size_t)255;
    float* f1 = (float*)(ws + off);
    off += (size_t)n * HEADS * sizeof(float);          off = (off + 255) & ~(size_t)255;
    float* f2 = (float*)(ws + off);
    off += (size_t)n * HEADS * sizeof(float);          off = (off + 255) & ~(size_t)255;
    int* row_ptr = (int*)(ws + off);

    dim3 blk(256);
    gemm_feats_kernel<<<dim3((n + BROWS - 1) / BROWS), blk, 0, stream>>>(
        x, W, a1, b1, a2, b2, feats, f1, f2, n);
    rowptr_kernel<<<dim3((n + 1 + 255) / 256), blk, 0, stream>>>(src, row_ptr, n, e);
    aggregate_kernel<<<dim3((n + 3) / 4), blk, 0, stream>>>(
        row_ptr, dst, feats, f1, f2, out, n);
}

// Round 2
// 239.297 us; speedup vs baseline: 1.2319x; 1.2319x over previous
//
#include <hip/hip_runtime.h>
#include <hip/hip_bf16.h>
#include <math.h>

#define HEADS 8
#define D_IN 128
#define D_HEAD 16
#define D_OUT 128  // HEADS * D_HEAD

typedef unsigned short ushort_t;
typedef unsigned int uint_t;
typedef __attribute__((ext_vector_type(8))) short short8;
typedef __attribute__((ext_vector_type(4))) float floatx4;

// ---------------- helpers ----------------
static __device__ inline uint_t f32_to_bf16(float f) {
    uint_t u = __float_as_uint(f);
    return (u + 0x7fffu + ((u >> 16) & 1u)) >> 16;  // RTNE
}
static __device__ inline uint_t pack_bf16(float lo, float hi) {
    return (f32_to_bf16(hi) << 16) | f32_to_bf16(lo);
}
static __device__ inline float bf_lo(uint_t p) { return __uint_as_float(p << 16); }
static __device__ inline float bf_hi(uint_t p) { return __uint_as_float(p & 0xffff0000u); }

// ---------------- kernel 0: W -> transposed bf16 layout ----------------
// Wbt[c][d] = bf16( W[c>>4][d][c&15] ),  c in [0,128) channel, d in [0,128)
__global__ __launch_bounds__(256) void wprep_kernel(
    const float* __restrict__ Wg, ushort_t* __restrict__ Wbt)
{
    int i = blockIdx.x * 256 + threadIdx.x;   // 0..16383
    int c = i >> 7, d = i & 127;
    float v = Wg[(size_t)(c >> 4) * (D_IN * D_HEAD) + d * D_HEAD + (c & 15)];
    Wbt[i] = (ushort_t)f32_to_bf16(v);
}

// ---------------- kernel 1: MFMA GEMM + f1/f2 epilogue ----------------
// Computes C^T tiles: D[m=channel][n=node] = sum_k Wbt[ch][k] * x_bf[node][k]
// 256 thr = 4 waves; block tile = 64 nodes x 128 channels; wave = 16 nodes.
__global__ __launch_bounds__(256) void gemm_feats_mfma(
    const float* __restrict__ x, const ushort_t* __restrict__ Wbt,
    const float* __restrict__ a1, const float* __restrict__ b1,
    const float* __restrict__ a2, const float* __restrict__ b2,
    ushort_t* __restrict__ feats, float* __restrict__ f1,
    float* __restrict__ f2, int n)
{
    __shared__ ushort_t Xs[64][136];   // stride 272 B = 17*16 (aligned, odd*16 -> 2-way banks)

    const int tid  = threadIdx.x;
    const int wave = tid >> 6;
    const int lane = tid & 63;
    const int row0 = blockIdx.x * 64;

    // ---- stage x tile (fp32 -> bf16) ----
    {
        const int r  = tid >> 2;            // 0..63
        const int c0 = (tid & 3) * 32;      // 0,32,64,96
        const bool valid = (row0 + r) < n;
        const float* xr = x + (size_t)(row0 + r) * D_IN + c0;
        uint_t buf[16];
#pragma unroll
        for (int q = 0; q < 8; ++q) {
            float4 v = make_float4(0.f, 0.f, 0.f, 0.f);
            if (valid) v = *(const float4*)(xr + q * 4);
            buf[2 * q]     = pack_bf16(v.x, v.y);
            buf[2 * q + 1] = pack_bf16(v.z, v.w);
        }
        uint4* dp = (uint4*)&Xs[r][c0];
#pragma unroll
        for (int q = 0; q < 4; ++q)
            dp[q] = make_uint4(buf[4 * q], buf[4 * q + 1], buf[4 * q + 2], buf[4 * q + 3]);
    }
    __syncthreads();

    const int m  = lane & 15;    // A row (channel within tile) / B col (node within wave tile)
    const int kg = lane >> 4;    // k-group (k = kg*8 + j)

    floatx4 acc[8];
#pragma unroll
    for (int ct = 0; ct < 8; ++ct) acc[ct] = (floatx4){0.f, 0.f, 0.f, 0.f};

#pragma unroll
    for (int ks = 0; ks < 4; ++ks) {
        short8 xb = *(const short8*)&Xs[16 * wave + m][ks * 32 + kg * 8];
#pragma unroll
        for (int ct = 0; ct < 8; ++ct) {
            short8 wa = *(const short8*)(Wbt + (size_t)(ct * 16 + m) * D_IN + ks * 32 + kg * 8);
            acc[ct] = __builtin_amdgcn_mfma_f32_16x16x32_bf16(wa, xb, acc[ct], 0, 0, 0);
        }
    }

    // ---- epilogue ----
    // D layout: col = lane&15 = node (within wave tile), row = kg*4 + reg = channel
    // within ct tile; global channel c = ct*16 + kg*4 + reg; head h = ct.
    const int node = row0 + wave * 16 + m;
    const bool valid = node < n;

    if (valid) {
#pragma unroll
        for (int ct = 0; ct < 8; ++ct) {
            uint_t lo = pack_bf16(acc[ct][0], acc[ct][1]);
            uint_t hi = pack_bf16(acc[ct][2], acc[ct][3]);
            *(uint2*)(feats + (size_t)node * D_OUT + ct * 16 + kg * 4) = make_uint2(lo, hi);
        }
    }

#pragma unroll
    for (int ct = 0; ct < 8; ++ct) {
        float p1 = 0.f, p2 = 0.f;
#pragma unroll
        for (int r = 0; r < 4; ++r) {
            const int o = kg * 4 + r;
            p1 = fmaf(acc[ct][r], a1[ct * D_HEAD + o], p1);
            p2 = fmaf(acc[ct][r], a2[ct * D_HEAD + o], p2);
        }
        p1 += __shfl_xor(p1, 16); p1 += __shfl_xor(p1, 32);
        p2 += __shfl_xor(p2, 16); p2 += __shfl_xor(p2, 32);
        if (kg == 0 && valid) {
            f1[(size_t)node * HEADS + ct] = p1 + b1[ct];
            f2[(size_t)node * HEADS + ct] = p2 + b2[ct];
        }
    }
}

// ---------------- kernel 2: CSR row_ptr from sorted src ----------------
__global__ __launch_bounds__(256) void rowptr_kernel(
    const int* __restrict__ src, int* __restrict__ row_ptr, int n, int e)
{
    int i = blockIdx.x * blockDim.x + threadIdx.x;
    if (i > n) return;
    int lo = 0, hi = e;
    while (lo < hi) {
        int mid = (lo + hi) >> 1;
        if (src[mid] < i) lo = mid + 1; else hi = mid;
    }
    row_ptr[i] = lo;  // lower_bound(src, i)
}

// ---------------- kernel 3: per-node aggregation (no-max softmax, unroll 4) ----
__global__ __launch_bounds__(256) void aggregate_kernel(
    const int* __restrict__ row_ptr, const int* __restrict__ dst,
    const ushort_t* __restrict__ feats,
    const float* __restrict__ f1, const float* __restrict__ f2,
    float* __restrict__ out, int n)
{
    int node = blockIdx.x * 4 + (threadIdx.x >> 6);
    node = __builtin_amdgcn_readfirstlane(node);   // wave-uniform -> scalar loads
    if (node >= n) return;
    const int lane = threadIdx.x & 63;
    const int h = lane >> 3;

    const float f1v   = f1[(size_t)node * HEADS + h];
    const int   start = row_ptr[node];
    const int   end   = row_ptr[node + 1];

    const float*    f2h = f2 + h;
    const ushort_t* fl  = feats + 2 * lane;

    float s = 0.f, ax = 0.f, ay = 0.f;
    int e = start;
    for (; e + 4 <= end; e += 4) {
        const int d0 = dst[e], d1 = dst[e + 1], d2 = dst[e + 2], d3 = dst[e + 3];
        const float g0 = f2h[d0 * HEADS], g1 = f2h[d1 * HEADS];
        const float g2 = f2h[d2 * HEADS], g3 = f2h[d3 * HEADS];
        const uint_t p0 = *(const uint_t*)(fl + d0 * D_OUT);
        const uint_t p1 = *(const uint_t*)(fl + d1 * D_OUT);
        const uint_t p2 = *(const uint_t*)(fl + d2 * D_OUT);
        const uint_t p3 = *(const uint_t*)(fl + d3 * D_OUT);
        float z0 = f1v + g0; z0 = fmaxf(z0, 0.2f * z0);
        float z1 = f1v + g1; z1 = fmaxf(z1, 0.2f * z1);
        float z2 = f1v + g2; z2 = fmaxf(z2, 0.2f * z2);
        float z3 = f1v + g3; z3 = fmaxf(z3, 0.2f * z3);
        const float w0 = __expf(z0), w1 = __expf(z1), w2 = __expf(z2), w3 = __expf(z3);
        s += (w0 + w1) + (w2 + w3);
        ax = fmaf(w0, bf_lo(p0), ax); ay = fmaf(w0, bf_hi(p0), ay);
        ax = fmaf(w1, bf_lo(p1), ax); ay = fmaf(w1, bf_hi(p1), ay);
        ax = fmaf(w2, bf_lo(p2), ax); ay = fmaf(w2, bf_hi(p2), ay);
        ax = fmaf(w3, bf_lo(p3), ax); ay = fmaf(w3, bf_hi(p3), ay);
    }
    for (; e < end; ++e) {
        const int d = dst[e];
        const float g = f2h[d * HEADS];
        const uint_t p = *(const uint_t*)(fl + d * D_OUT);
        float z = f1v + g; z = fmaxf(z, 0.2f * z);
        const float w = __expf(z);
        s += w;
        ax = fmaf(w, bf_lo(p), ax); ay = fmaf(w, bf_hi(p), ay);
    }

    float rx = 0.f, ry = 0.f;
    if (end > start) {
        rx = ax / s;
        ry = ay / s;
        rx = rx > 0.f ? rx : expm1f(rx);   // elu
        ry = ry > 0.f ? ry : expm1f(ry);
    }
    *(float2*)(out + (size_t)node * D_OUT + 2 * lane) = make_float2(rx, ry);
}

// ---------------- launch ----------------
extern "C" void kernel_launch(void* const* d_in, const int* in_sizes, int n_in,
                              void* d_out, int out_size, void* d_ws, size_t ws_size,
                              hipStream_t stream)
{
    const float* x  = (const float*)d_in[0];
    const float* W  = (const float*)d_in[1];
    const float* a1 = (const float*)d_in[2];
    const float* b1 = (const float*)d_in[3];
    const float* a2 = (const float*)d_in[4];
    const float* b2 = (const float*)d_in[5];
    const int* src  = (const int*)d_in[6];
    const int* dst  = (const int*)d_in[7];
    float* out = (float*)d_out;

    const int n = in_sizes[0] / D_IN;   // 100000
    const int e = in_sizes[6];          // 1600000

    // workspace carve-up
    char* ws = (char*)d_ws;
    size_t off = 0;
    ushort_t* feats = (ushort_t*)(ws + off);
    off += (size_t)n * D_OUT * sizeof(ushort_t); off = (off + 255) & ~(size_t)255;
    float* f1 = (float*)(ws + off);
    off += (size_t)n * HEADS * sizeof(float);    off = (off + 255) & ~(size_t)255;
    float* f2 = (float*)(ws + off);
    off += (size_t)n * HEADS * sizeof(float);    off = (off + 255) & ~(size_t)255;
    int* row_ptr = (int*)(ws + off);
    off += (size_t)(n + 1) * sizeof(int);        off = (off + 255) & ~(size_t)255;
    ushort_t* Wbt = (ushort_t*)(ws + off);

    dim3 blk(256);
    wprep_kernel<<<dim3(64), blk, 0, stream>>>(W, Wbt);
    rowptr_kernel<<<dim3((n + 1 + 255) / 256), blk, 0, stream>>>(src, row_ptr, n, e);
    gemm_feats_mfma<<<dim3((n + 63) / 64), blk, 0, stream>>>(
        x, Wbt, a1, b1, a2, b2, feats, f1, f2, n);
    aggregate_kernel<<<dim3((n + 3) / 4), blk, 0, stream>>>(
        row_ptr, dst, feats, f1, f2, out, n);
}

// Round 3
// 220.907 us; speedup vs baseline: 1.3345x; 1.0832x over previous
//
#include <hip/hip_runtime.h>
#include <hip/hip_bf16.h>
#include <math.h>

#define HEADS 8
#define D_IN 128
#define D_HEAD 16
#define D_OUT 128  // HEADS * D_HEAD

typedef unsigned short ushort_t;
typedef unsigned int uint_t;
typedef __attribute__((ext_vector_type(8))) short short8;
typedef __attribute__((ext_vector_type(4))) float floatx4;

// ---------------- helpers ----------------
static __device__ inline uint_t f32_to_bf16(float f) {
    uint_t u = __float_as_uint(f);
    return (u + 0x7fffu + ((u >> 16) & 1u)) >> 16;  // RTNE
}
static __device__ inline uint_t pack_bf16(float lo, float hi) {
    return (f32_to_bf16(hi) << 16) | f32_to_bf16(lo);
}
static __device__ inline float bf_lo(uint_t p) { return __uint_as_float(p << 16); }
static __device__ inline float bf_hi(uint_t p) { return __uint_as_float(p & 0xffff0000u); }

// ---------------- kernel 0: prep = W->fragment-major bf16  +  CSR row_ptr ----
// Wfrag layout: t = (((ct*4+ks)*64)+lane)*8 + j  holds bf16(W[ct][ks*32+(lane>>4)*8+j][lane&15])
// -> in gemm, wa load for (ct,ks) is wave-contiguous 1 KB.
#define PREP_WBLOCKS 64
__global__ __launch_bounds__(256) void prep_kernel(
    const float* __restrict__ Wg, ushort_t* __restrict__ Wfrag,
    const int* __restrict__ src, int* __restrict__ row_ptr, int n, int e)
{
    if (blockIdx.x < PREP_WBLOCKS) {
        int t = blockIdx.x * 256 + threadIdx.x;   // 0..16383
        int j    = t & 7;
        int lane = (t >> 3) & 63;
        int ks   = (t >> 9) & 3;
        int ct   = t >> 11;
        int k = ks * 32 + (lane >> 4) * 8 + j;
        int m = lane & 15;
        float v = Wg[(size_t)ct * (D_IN * D_HEAD) + k * D_HEAD + m];
        Wfrag[t] = (ushort_t)f32_to_bf16(v);
    } else {
        int i = (blockIdx.x - PREP_WBLOCKS) * 256 + threadIdx.x;
        if (i > n) return;
        int lo = 0, hi = e;
        while (lo < hi) {
            int mid = (lo + hi) >> 1;
            if (src[mid] < i) lo = mid + 1; else hi = mid;
        }
        row_ptr[i] = lo;  // lower_bound(src, i)
    }
}

// ---------------- kernel 1: MFMA GEMM + f1/f2 epilogue ----------------
// Block: 256 thr = 4 waves; tile = 128 nodes x 128 channels.
// Wave handles 32 nodes (2 node-tiles) x 128 ch (8 ct); each wa feeds 2 MFMAs.
__global__ __launch_bounds__(256) void gemm_feats_mfma(
    const float* __restrict__ x, const ushort_t* __restrict__ Wfrag,
    const float* __restrict__ a1, const float* __restrict__ b1,
    const float* __restrict__ a2, const float* __restrict__ b2,
    ushort_t* __restrict__ feats, float* __restrict__ f1,
    float* __restrict__ f2, int n)
{
    __shared__ ushort_t Xs[128][136];  // row stride 272 B = 17*16 (16B-aligned, 2-way banks only)

    const int tid  = threadIdx.x;
    const int wave = tid >> 6;
    const int lane = tid & 63;
    const int row0 = blockIdx.x * 128;

    // ---- stage x tile (fp32 -> bf16), fully coalesced 16 B/lane ----
#pragma unroll
    for (int it = 0; it < 16; ++it) {
        int idx = it * 256 + tid;        // float4 id, 0..4095 (128 rows x 32)
        int r   = idx >> 5;
        int c4  = (idx & 31) * 4;
        float4 v = make_float4(0.f, 0.f, 0.f, 0.f);
        if (row0 + r < n) v = *(const float4*)(x + (size_t)(row0 + r) * D_IN + c4);
        *(uint2*)&Xs[r][c4] = make_uint2(pack_bf16(v.x, v.y), pack_bf16(v.z, v.w));
    }
    __syncthreads();

    const int m  = lane & 15;
    const int kg = lane >> 4;

    floatx4 acc[2][8];
#pragma unroll
    for (int nt = 0; nt < 2; ++nt)
#pragma unroll
        for (int ct = 0; ct < 8; ++ct) acc[nt][ct] = (floatx4){0.f, 0.f, 0.f, 0.f};

#pragma unroll
    for (int ks = 0; ks < 4; ++ks) {
        short8 xb0 = *(const short8*)&Xs[wave * 32 + m][ks * 32 + kg * 8];
        short8 xb1 = *(const short8*)&Xs[wave * 32 + 16 + m][ks * 32 + kg * 8];
#pragma unroll
        for (int ct = 0; ct < 8; ++ct) {
            short8 wa = *(const short8*)(Wfrag + ((size_t)(ct * 4 + ks) * 64 + lane) * 8);
            acc[0][ct] = __builtin_amdgcn_mfma_f32_16x16x32_bf16(wa, xb0, acc[0][ct], 0, 0, 0);
            acc[1][ct] = __builtin_amdgcn_mfma_f32_16x16x32_bf16(wa, xb1, acc[1][ct], 0, 0, 0);
        }
    }

    // ---- epilogue ----
    // D layout: col(lane&15) = node within tile; row = kg*4 + reg = channel
    // within ct tile; global channel c = ct*16 + kg*4 + reg; head = ct.
#pragma unroll
    for (int nt = 0; nt < 2; ++nt) {
        const int node = row0 + wave * 32 + nt * 16 + m;
        const bool valid = node < n;
        if (valid) {
#pragma unroll
            for (int ct = 0; ct < 8; ++ct) {
                uint_t lo = pack_bf16(acc[nt][ct][0], acc[nt][ct][1]);
                uint_t hi = pack_bf16(acc[nt][ct][2], acc[nt][ct][3]);
                *(uint2*)(feats + (size_t)node * D_OUT + ct * 16 + kg * 4) = make_uint2(lo, hi);
            }
        }
#pragma unroll
        for (int ct = 0; ct < 8; ++ct) {
            float4 A1 = *(const float4*)(a1 + ct * D_HEAD + kg * 4);
            float4 A2 = *(const float4*)(a2 + ct * D_HEAD + kg * 4);
            float p1 = acc[nt][ct][0] * A1.x + acc[nt][ct][1] * A1.y +
                       acc[nt][ct][2] * A1.z + acc[nt][ct][3] * A1.w;
            float p2 = acc[nt][ct][0] * A2.x + acc[nt][ct][1] * A2.y +
                       acc[nt][ct][2] * A2.z + acc[nt][ct][3] * A2.w;
            p1 += __shfl_xor(p1, 16); p1 += __shfl_xor(p1, 32);
            p2 += __shfl_xor(p2, 16); p2 += __shfl_xor(p2, 32);
            if (kg == 0 && valid) {
                f1[(size_t)node * HEADS + ct] = p1 + b1[ct];
                f2[(size_t)node * HEADS + ct] = p2 + b2[ct];
            }
        }
    }
}

// ---------------- kernel 2: per-node aggregation (no-max softmax, unroll 8) ----
__global__ __launch_bounds__(256) void aggregate_kernel(
    const int* __restrict__ row_ptr, const int* __restrict__ dst,
    const ushort_t* __restrict__ feats,
    const float* __restrict__ f1, const float* __restrict__ f2,
    float* __restrict__ out, int n)
{
    int node = blockIdx.x * 4 + (threadIdx.x >> 6);
    node = __builtin_amdgcn_readfirstlane(node);   // wave-uniform -> scalar loads
    if (node >= n) return;
    const int lane = threadIdx.x & 63;
    const int h = lane >> 3;

    const float f1v   = f1[(size_t)node * HEADS + h];
    const int   start = row_ptr[node];
    const int   end   = row_ptr[node + 1];

    const float*    f2h = f2 + h;
    const ushort_t* fl  = feats + 2 * lane;

    float s = 0.f, ax = 0.f, ay = 0.f;
    int e = start;
    for (; e + 8 <= end; e += 8) {
        int d[8]; float g[8]; uint_t p[8];
#pragma unroll
        for (int q = 0; q < 8; ++q) d[q] = dst[e + q];
#pragma unroll
        for (int q = 0; q < 8; ++q) {
            g[q] = f2h[d[q] * HEADS];
            p[q] = *(const uint_t*)(fl + d[q] * D_OUT);
        }
#pragma unroll
        for (int q = 0; q < 8; ++q) {
            float z = f1v + g[q];
            z = fmaxf(z, 0.2f * z);           // leaky_relu(0.2)
            float w = __expf(z);
            s += w;
            ax = fmaf(w, bf_lo(p[q]), ax);
            ay = fmaf(w, bf_hi(p[q]), ay);
        }
    }
    for (; e < end; ++e) {
        const int d = dst[e];
        const float g = f2h[d * HEADS];
        const uint_t p = *(const uint_t*)(fl + d * D_OUT);
        float z = f1v + g;
        z = fmaxf(z, 0.2f * z);
        const float w = __expf(z);
        s += w;
        ax = fmaf(w, bf_lo(p), ax);
        ay = fmaf(w, bf_hi(p), ay);
    }

    float rx = 0.f, ry = 0.f;
    if (end > start) {
        rx = ax / s;
        ry = ay / s;
        rx = rx > 0.f ? rx : expm1f(rx);   // elu
        ry = ry > 0.f ? ry : expm1f(ry);
    }
    *(float2*)(out + (size_t)node * D_OUT + 2 * lane) = make_float2(rx, ry);
}

// ---------------- launch ----------------
extern "C" void kernel_launch(void* const* d_in, const int* in_sizes, int n_in,
                              void* d_out, int out_size, void* d_ws, size_t ws_size,
                              hipStream_t stream)
{
    const float* x  = (const float*)d_in[0];
    const float* W  = (const float*)d_in[1];
    const float* a1 = (const float*)d_in[2];
    const float* b1 = (const float*)d_in[3];
    const float* a2 = (const float*)d_in[4];
    const float* b2 = (const float*)d_in[5];
    const int* src  = (const int*)d_in[6];
    const int* dst  = (const int*)d_in[7];
    float* out = (float*)d_out;

    const int n = in_sizes[0] / D_IN;   // 100000
    const int e = in_sizes[6];          // 1600000

    // workspace carve-up
    char* ws = (char*)d_ws;
    size_t off = 0;
    ushort_t* feats = (ushort_t*)(ws + off);
    off += (size_t)n * D_OUT * sizeof(ushort_t); off = (off + 255) & ~(size_t)255;
    float* f1 = (float*)(ws + off);
    off += (size_t)n * HEADS * sizeof(float);    off = (off + 255) & ~(size_t)255;
    float* f2 = (float*)(ws + off);
    off += (size_t)n * HEADS * sizeof(float);    off = (off + 255) & ~(size_t)255;
    int* row_ptr = (int*)(ws + off);
    off += (size_t)(n + 1) * sizeof(int);        off = (off + 255) & ~(size_t)255;
    ushort_t* Wfrag = (ushort_t*)(ws + off);

    dim3 blk(256);
    const int rp_blocks = (n + 1 + 255) / 256;
    prep_kernel<<<dim3(PREP_WBLOCKS + rp_blocks), blk, 0, stream>>>(
        W, Wfrag, src, row_ptr, n, e);
    gemm_feats_mfma<<<dim3((n + 127) / 128), blk, 0, stream>>>(
        x, Wfrag, a1, b1, a2, b2, feats, f1, f2, n);
    aggregate_kernel<<<dim3((n + 3) / 4), blk, 0, stream>>>(
        row_ptr, dst, feats, f1, f2, out, n);
}

// Round 4
// 217.629 us; speedup vs baseline: 1.3546x; 1.0151x over previous
//
#include <hip/hip_runtime.h>
#include <hip/hip_bf16.h>
#include <math.h>

#define HEADS 8
#define D_IN 128
#define D_HEAD 16
#define D_OUT 128  // HEADS * D_HEAD

typedef unsigned short ushort_t;
typedef unsigned int uint_t;
typedef __attribute__((ext_vector_type(8))) short short8;
typedef __attribute__((ext_vector_type(4))) float floatx4;

// ---------------- helpers ----------------
static __device__ inline uint_t f32_to_bf16(float f) {
    uint_t u = __float_as_uint(f);
    return (u + 0x7fffu + ((u >> 16) & 1u)) >> 16;  // RTNE
}
static __device__ inline uint_t pack_bf16(float lo, float hi) {
    return (f32_to_bf16(hi) << 16) | f32_to_bf16(lo);
}
static __device__ inline float bf_lo(uint_t p) { return __uint_as_float(p << 16); }
static __device__ inline float bf_hi(uint_t p) { return __uint_as_float(p & 0xffff0000u); }

// ---------------- kernel 0: prep = W->fragment-major bf16  +  CSR row_ptr ----
// Wfrag layout: t = (((ct*4+ks)*64)+lane)*8 + j holds bf16(W[ct][ks*32+(lane>>4)*8+j][lane&15])
// rowptr: edge-parallel boundary detection over sorted src (NO binary search):
//   thread e fills row_ptr[i] = e for all i in (src[e-1], src[e]];
//   thread E fills (src[E-1], n]. Each row_ptr entry written exactly once.
#define PREP_WBLOCKS 64
__global__ __launch_bounds__(256) void prep_kernel(
    const float* __restrict__ Wg, ushort_t* __restrict__ Wfrag,
    const int* __restrict__ src, int* __restrict__ row_ptr, int n, int e)
{
    if (blockIdx.x < PREP_WBLOCKS) {
        int t = blockIdx.x * 256 + threadIdx.x;   // 0..16383
        int j    = t & 7;
        int lane = (t >> 3) & 63;
        int ks   = (t >> 9) & 3;
        int ct   = t >> 11;
        int k = ks * 32 + (lane >> 4) * 8 + j;
        int m = lane & 15;
        float v = Wg[(size_t)ct * (D_IN * D_HEAD) + k * D_HEAD + m];
        Wfrag[t] = (ushort_t)f32_to_bf16(v);
    } else {
        int i = (blockIdx.x - PREP_WBLOCKS) * 256 + threadIdx.x;  // 0..e
        if (i > e) return;
        int sp = (i == 0) ? -1 : src[i - 1];
        int sc = (i == e) ? n  : src[i];
        for (int node = sp + 1; node <= sc; ++node) row_ptr[node] = i;
    }
}

// ---------------- kernel 1: MFMA GEMM + f1/f2 epilogue ----------------
// Block: 256 thr = 4 waves; tile = 128 nodes x 128 channels.
// Wave handles 32 nodes (2 node-tiles) x 128 ch (8 ct); each wa feeds 2 MFMAs.
__global__ __launch_bounds__(256) void gemm_feats_mfma(
    const float* __restrict__ x, const ushort_t* __restrict__ Wfrag,
    const float* __restrict__ a1, const float* __restrict__ b1,
    const float* __restrict__ a2, const float* __restrict__ b2,
    ushort_t* __restrict__ feats, float* __restrict__ f1,
    float* __restrict__ f2, int n)
{
    __shared__ ushort_t Xs[128][136];  // row stride 272 B = 17*16 (16B-aligned, 2-way banks only)

    const int tid  = threadIdx.x;
    const int wave = tid >> 6;
    const int lane = tid & 63;
    const int row0 = blockIdx.x * 128;

    // ---- stage x tile (fp32 -> bf16), fully coalesced 16 B/lane ----
#pragma unroll
    for (int it = 0; it < 16; ++it) {
        int idx = it * 256 + tid;        // float4 id, 0..4095 (128 rows x 32)
        int r   = idx >> 5;
        int c4  = (idx & 31) * 4;
        float4 v = make_float4(0.f, 0.f, 0.f, 0.f);
        if (row0 + r < n) v = *(const float4*)(x + (size_t)(row0 + r) * D_IN + c4);
        *(uint2*)&Xs[r][c4] = make_uint2(pack_bf16(v.x, v.y), pack_bf16(v.z, v.w));
    }
    __syncthreads();

    const int m  = lane & 15;
    const int kg = lane >> 4;

    floatx4 acc[2][8];
#pragma unroll
    for (int nt = 0; nt < 2; ++nt)
#pragma unroll
        for (int ct = 0; ct < 8; ++ct) acc[nt][ct] = (floatx4){0.f, 0.f, 0.f, 0.f};

#pragma unroll
    for (int ks = 0; ks < 4; ++ks) {
        short8 xb0 = *(const short8*)&Xs[wave * 32 + m][ks * 32 + kg * 8];
        short8 xb1 = *(const short8*)&Xs[wave * 32 + 16 + m][ks * 32 + kg * 8];
#pragma unroll
        for (int ct = 0; ct < 8; ++ct) {
            short8 wa = *(const short8*)(Wfrag + ((size_t)(ct * 4 + ks) * 64 + lane) * 8);
            acc[0][ct] = __builtin_amdgcn_mfma_f32_16x16x32_bf16(wa, xb0, acc[0][ct], 0, 0, 0);
            acc[1][ct] = __builtin_amdgcn_mfma_f32_16x16x32_bf16(wa, xb1, acc[1][ct], 0, 0, 0);
        }
    }

    // ---- epilogue ----
    // D layout: col(lane&15) = node within tile; row = kg*4 + reg = channel
    // within ct tile; global channel c = ct*16 + kg*4 + reg; head = ct.
#pragma unroll
    for (int nt = 0; nt < 2; ++nt) {
        const int node = row0 + wave * 32 + nt * 16 + m;
        const bool valid = node < n;
        if (valid) {
#pragma unroll
            for (int ct = 0; ct < 8; ++ct) {
                uint_t lo = pack_bf16(acc[nt][ct][0], acc[nt][ct][1]);
                uint_t hi = pack_bf16(acc[nt][ct][2], acc[nt][ct][3]);
                *(uint2*)(feats + (size_t)node * D_OUT + ct * 16 + kg * 4) = make_uint2(lo, hi);
            }
        }
#pragma unroll
        for (int ct = 0; ct < 8; ++ct) {
            float4 A1 = *(const float4*)(a1 + ct * D_HEAD + kg * 4);
            float4 A2 = *(const float4*)(a2 + ct * D_HEAD + kg * 4);
            float p1 = acc[nt][ct][0] * A1.x + acc[nt][ct][1] * A1.y +
                       acc[nt][ct][2] * A1.z + acc[nt][ct][3] * A1.w;
            float p2 = acc[nt][ct][0] * A2.x + acc[nt][ct][1] * A2.y +
                       acc[nt][ct][2] * A2.z + acc[nt][ct][3] * A2.w;
            p1 += __shfl_xor(p1, 16); p1 += __shfl_xor(p1, 32);
            p2 += __shfl_xor(p2, 16); p2 += __shfl_xor(p2, 32);
            if (kg == 0 && valid) {
                f1[(size_t)node * HEADS + ct] = p1 + b1[ct];
                f2[(size_t)node * HEADS + ct] = p2 + b2[ct];
            }
        }
    }
}

// ---------------- kernel 2: per-node aggregation ----------------
// one wave per node; lane owns out channels (2*lane, 2*lane+1); head = lane>>3.
// Weight computation de-duplicated: in each 8-edge batch, lane (h=l>>3,q=l&7)
// computes w for edge q / head h (1 gather + 1 exp), then __shfl broadcasts
// w_q within the head group.
__global__ __launch_bounds__(256) void aggregate_kernel(
    const int* __restrict__ row_ptr, const int* __restrict__ dst,
    const ushort_t* __restrict__ feats,
    const float* __restrict__ f1, const float* __restrict__ f2,
    float* __restrict__ out, int n)
{
    int node = blockIdx.x * 4 + (threadIdx.x >> 6);
    node = __builtin_amdgcn_readfirstlane(node);   // wave-uniform -> scalar loads
    if (node >= n) return;
    const int lane = threadIdx.x & 63;
    const int h = lane >> 3;

    const float f1v   = f1[(size_t)node * HEADS + h];
    const int   start = row_ptr[node];
    const int   end   = row_ptr[node + 1];

    const ushort_t* fl = feats + 2 * lane;

    float s = 0.f, ax = 0.f, ay = 0.f;
    int e = start;
    for (; e + 8 <= end; e += 8) {
        int d[8];
#pragma unroll
        for (int q = 0; q < 8; ++q) d[q] = dst[e + q];          // scalar loads
        // per-lane weight for edge (lane&7), head (lane>>3)
        const int   dq = dst[e + (lane & 7)];                   // vector load
        const float g  = f2[(size_t)dq * HEADS + h];
        float z = f1v + g;
        z = fmaxf(z, 0.2f * z);                                 // leaky_relu
        const float w = __expf(z);
        uint_t p[8];
#pragma unroll
        for (int q = 0; q < 8; ++q)
            p[q] = *(const uint_t*)(fl + (size_t)d[q] * D_OUT); // saddr gathers
#pragma unroll
        for (int q = 0; q < 8; ++q) {
            const float wq = __shfl(w, (lane & 56) | q);
            s += wq;
            ax = fmaf(wq, bf_lo(p[q]), ax);
            ay = fmaf(wq, bf_hi(p[q]), ay);
        }
    }
    for (; e < end; ++e) {
        const int d = dst[e];
        const float g = f2[(size_t)d * HEADS + h];
        const uint_t p = *(const uint_t*)(fl + (size_t)d * D_OUT);
        float z = f1v + g;
        z = fmaxf(z, 0.2f * z);
        const float w = __expf(z);
        s += w;
        ax = fmaf(w, bf_lo(p), ax);
        ay = fmaf(w, bf_hi(p), ay);
    }

    float rx = 0.f, ry = 0.f;
    if (end > start) {
        rx = ax / s;
        ry = ay / s;
        rx = rx > 0.f ? rx : expm1f(rx);   // elu
        ry = ry > 0.f ? ry : expm1f(ry);
    }
    *(float2*)(out + (size_t)node * D_OUT + 2 * lane) = make_float2(rx, ry);
}

// ---------------- launch ----------------
extern "C" void kernel_launch(void* const* d_in, const int* in_sizes, int n_in,
                              void* d_out, int out_size, void* d_ws, size_t ws_size,
                              hipStream_t stream)
{
    const float* x  = (const float*)d_in[0];
    const float* W  = (const float*)d_in[1];
    const float* a1 = (const float*)d_in[2];
    const float* b1 = (const float*)d_in[3];
    const float* a2 = (const float*)d_in[4];
    const float* b2 = (const float*)d_in[5];
    const int* src  = (const int*)d_in[6];
    const int* dst  = (const int*)d_in[7];
    float* out = (float*)d_out;

    const int n = in_sizes[0] / D_IN;   // 100000
    const int e = in_sizes[6];          // 1600000

    // workspace carve-up
    char* ws = (char*)d_ws;
    size_t off = 0;
    ushort_t* feats = (ushort_t*)(ws + off);
    off += (size_t)n * D_OUT * sizeof(ushort_t); off = (off + 255) & ~(size_t)255;
    float* f1 = (float*)(ws + off);
    off += (size_t)n * HEADS * sizeof(float);    off = (off + 255) & ~(size_t)255;
    float* f2 = (float*)(ws + off);
    off += (size_t)n * HEADS * sizeof(float);    off = (off + 255) & ~(size_t)255;
    int* row_ptr = (int*)(ws + off);
    off += (size_t)(n + 1) * sizeof(int);        off = (off + 255) & ~(size_t)255;
    ushort_t* Wfrag = (ushort_t*)(ws + off);

    dim3 blk(256);
    const int rp_blocks = (e + 1 + 255) / 256;
    prep_kernel<<<dim3(PREP_WBLOCKS + rp_blocks), blk, 0, stream>>>(
        W, Wfrag, src, row_ptr, n, e);
    gemm_feats_mfma<<<dim3((n + 127) / 128), blk, 0, stream>>>(
        x, Wfrag, a1, b1, a2, b2, feats, f1, f2, n);
    aggregate_kernel<<<dim3((n + 3) / 4), blk, 0, stream>>>(
        row_ptr, dst, feats, f1, f2, out, n);
}